// Round 12
// baseline (261.255 us; speedup 1.0000x reference)
//
#include <hip/hip_runtime.h>
#include <hip/hip_bf16.h>
#include <math.h>

#define NA 8192
#define NB 131072
#define NG 16
#define NSHARD 16
#define NIT 16            // (NA/NSHARD)/32

// workspace layout (float offsets)
#define OFF_BH    0u          // 3*32*1024 bf16 = 49152 f
#define OFF_VB    49152u      // 24576 f
#define OFF_CNT   73728u      // 8192 int
#define OFF_CUR   81920u      // 8192 int
#define OFF_RP    90112u      // 8192 int
#define OFF_ISLOT 98304u      // 131072 int (edge -> dst-sorted slot)
#define OFF_QH    229376u     // 8192*32 bf16 = 131072 f each
#define OFF_QL    360448u
#define OFF_KH    491520u
#define OFF_KL    622592u
#define OFF_VTH   753664u
#define OFF_VTL   884736u
#define OFF_MSG   1015808u    // 3*131072*32 bf16 = 6291456 f
#define OFF_NUM   1015808u    // ALIAS of MSG (msgbuf dead before attn writes num)
#define OFF_DEN   7307264u    // 131072 f  (end ~29.8 MB)

typedef __attribute__((ext_vector_type(8))) short short8;
typedef __attribute__((ext_vector_type(4))) float f4;
typedef __attribute__((ext_vector_type(2))) float f2;
typedef __attribute__((ext_vector_type(2))) unsigned int uint2v;

__device__ inline unsigned short bfb(float x) {
    __hip_bfloat16 b = __float2bfloat16(x);   // RNE
    return reinterpret_cast<unsigned short&>(b);
}
__device__ inline float bf2f(unsigned short u) {
    unsigned int x = ((unsigned int)u) << 16;
    return __uint_as_float(x);
}
__device__ inline unsigned int pk2(float x, float y) {
    __hip_bfloat162 t = __float22bfloat162_rn(make_float2(x, y));
    union { __hip_bfloat162 b; unsigned int u; } cv;
    cv.b = t;
    return cv.u;
}

// Fused: edge-dst histogram (all 512 blocks) + prep_bh (bid<96) + prep_v (96<=bid<144)
__global__ __launch_bounds__(256) void prep_all(
    const float* __restrict__ We, const float* __restrict__ state,
    const float* __restrict__ be, const int* __restrict__ pair,
    unsigned short* __restrict__ Bh, unsigned short* __restrict__ Vb,
    int* __restrict__ cnt)
{
    const int bid = blockIdx.x, tid = threadIdx.x;
    const int e = bid * 256 + tid;
    atomicAdd(&cnt[pair[2 * e]], 1);
    if (bid < 96) {
        int idx = bid * 256 + tid;
        int hc = idx >> 8;
        int n4 = (idx & 255) * 4;
        const float4 v = *(const float4*)(We + ((size_t)((hc >> 5) * 64 + (hc & 31))) * 1024 + n4);
        unsigned short* d = Bh + (size_t)hc * 1024 + n4;
        d[0] = bfb(v.x); d[1] = bfb(v.y); d[2] = bfb(v.z); d[3] = bfb(v.w);
    } else if (bid < 144) {
        int b2 = bid - 96;
        int h = b2 >> 4, g = b2 & 15;
        const float* st = state + g * 32;
        const float* W  = We + ((size_t)h * 64 + 32) * 1024;
        const float* bb = be + (size_t)h * 1024;
        int n = tid * 4;
        float4 acc = *(const float4*)(bb + n);
        for (int c = 0; c < 32; ++c) {
            float s = st[c];
            const float4 w = *(const float4*)(W + c * 1024 + n);
            acc.x += s * w.x; acc.y += s * w.y; acc.z += s * w.z; acc.w += s * w.w;
        }
        unsigned short* d = Vb + ((size_t)h * 16 + g) * 1024 + n;
        d[0] = bfb(acc.x); d[1] = bfb(acc.y); d[2] = bfb(acc.z); d[3] = bfb(acc.w);
    }
}

// Exclusive scan of 8192 counts -> cur (scatter cursors) + rp (rowptr)
__global__ __launch_bounds__(256) void scan_kernel(const int* __restrict__ cnt,
                                                   int* __restrict__ cur,
                                                   int* __restrict__ rp)
{
    __shared__ int part[256];
    const int t = threadIdx.x;
    const int base = t * 32;
    int loc[32];
    int s = 0;
    #pragma unroll
    for (int k = 0; k < 32; ++k) { loc[k] = cnt[base + k]; s += loc[k]; }
    part[t] = s;
    __syncthreads();
    for (int off = 1; off < 256; off <<= 1) {
        int add = (t >= off) ? part[t - off] : 0;
        __syncthreads();
        part[t] += add;
        __syncthreads();
    }
    int excl = part[t] - s;
    #pragma unroll
    for (int k = 0; k < 32; ++k) {
        cur[base + k] = excl; rp[base + k] = excl; excl += loc[k];
    }
}

// islot[e] = dst-sorted slot of edge e
__global__ __launch_bounds__(256) void scatter_kernel(const int* __restrict__ pair,
                                                      int* __restrict__ cur,
                                                      int* __restrict__ islot)
{
    const int e = blockIdx.x * 256 + threadIdx.x;
    const int d = pair[2 * e];
    islot[e] = atomicAdd(&cur[d], 1);
}

// MFMA edge-message GEMM, ALL 3 HEADS per wave (A-frag amortized over 6 MFMA).
// Block = 64 edges; wave = 16 edges x 3 heads x 2 N-tiles (acc 24 VGPR).
// Grid 2048 -> 8 blocks/CU. Epilogue = scattered streaming bf16 stores (islot).
__global__ __launch_bounds__(256) void msg_mfma(
    const float* __restrict__ atom, const float* __restrict__ bond,
    const unsigned short* __restrict__ Bh, const unsigned short* __restrict__ Vb,
    const int* __restrict__ pair, const int* __restrict__ bg,
    const int* __restrict__ islot, unsigned short* __restrict__ msgbuf)
{
    __shared__ float bl[64 * 36];
    __shared__ int gmm[2];
    const int tid = threadIdx.x;
    const int e0 = blockIdx.x * 64;
    for (int x = tid; x < 512; x += 256) {        // stage bond[e0:e0+64]
        int e = x >> 3, c4 = (x & 7) << 2;
        float4 v = *(const float4*)(bond + (size_t)(e0 + e) * 32 + c4);
        float* d = &bl[e * 36 + c4];
        d[0] = v.x; d[1] = v.y; d[2] = v.z; d[3] = v.w;
    }
    if (tid == 0) { gmm[0] = bg[e0]; gmm[1] = bg[e0 + 63]; }

    const int wave = tid >> 6, lane = tid & 63;
    const int ln = lane & 15, quad = lane >> 4;
    const int em = e0 + wave * 16 + ln;
    const int src = pair[2 * em + 1];
    const int gv = bg[em];
    f2 np[4];
    {
        const float* p = atom + (size_t)src * 32 + quad * 8;
        float4 a = *(const float4*)p, b = *(const float4*)(p + 4);
        np[0] = f2{a.x, a.y}; np[1] = f2{a.z, a.w};
        np[2] = f2{b.x, b.y}; np[3] = f2{b.z, b.w};
    }
    __syncthreads();
    f4 acc[3][2];
    #pragma unroll
    for (int h = 0; h < 3; ++h) { acc[h][0] = f4{0,0,0,0}; acc[h][1] = f4{0,0,0,0}; }

    const unsigned short* bp = Bh + ln * 32 + quad * 8;
    const int bo = (wave * 16 + ln) * 36;
    for (int c4 = 0; c4 < 32; c4 += 4) {
        f4 cv = *(const f4*)&bl[bo + c4];         // ds_read_b128: 4 bond coeffs
        #pragma unroll
        for (int u = 0; u < 4; ++u) {
            const int c = c4 + u;
            const float c0 = cv[u];
            union { unsigned int u4[4]; short8 s; } A;
            #pragma unroll
            for (int q2 = 0; q2 < 4; ++q2) {
                f2 p = c0 * np[q2];
                A.u4[q2] = pk2(p.x, p.y);
            }
            #pragma unroll
            for (int h = 0; h < 3; ++h) {
                const unsigned short* bpc = bp + ((size_t)(h * 32 + c)) * 1024;
                short8 b0 = *(const short8*)bpc;
                short8 b1 = *(const short8*)(bpc + 512);
                acc[h][0] = __builtin_amdgcn_mfma_f32_16x16x32_bf16(A.s, b0, acc[h][0], 0, 0, 0);
                acc[h][1] = __builtin_amdgcn_mfma_f32_16x16x32_bf16(A.s, b1, acc[h][1], 0, 0, 0);
            }
        }
    }
    // state/V term (bg sorted: gmax-gmin small)
    union { unsigned int u4[4]; short8 s; } NBv;
    #pragma unroll
    for (int q2 = 0; q2 < 4; ++q2) NBv.u4[q2] = pk2(np[q2].x, np[q2].y);
    const short8 zz = {0,0,0,0,0,0,0,0};
    const int gmin = gmm[0], gmax = gmm[1];
    for (int g = gmin; g <= gmax; ++g) {
        short8 a = (gv == g) ? NBv.s : zz;
        #pragma unroll
        for (int h = 0; h < 3; ++h) {
            const unsigned short* vp = Vb + ((size_t)h * 16 + g) * 1024 + ln * 32 + quad * 8;
            short8 b0 = *(const short8*)vp;
            short8 b1 = *(const short8*)(vp + 512);
            acc[h][0] = __builtin_amdgcn_mfma_f32_16x16x32_bf16(a, b0, acc[h][0], 0, 0, 0);
            acc[h][1] = __builtin_amdgcn_mfma_f32_16x16x32_bf16(a, b1, acc[h][1], 0, 0, 0);
        }
    }
    // epilogue: dst-sorted streaming stores
    const int eb = e0 + wave * 16 + quad * 4;
    int4 sv = *(const int4*)(islot + eb);
    const int sl[4] = {sv.x, sv.y, sv.z, sv.w};
    #pragma unroll
    for (int r = 0; r < 4; ++r) {
        #pragma unroll
        for (int h = 0; h < 3; ++h) {
            unsigned short* d = msgbuf + ((size_t)h * NB + sl[r]) * 32;
            d[ln]      = bfb(acc[h][0][r]);
            d[16 + ln] = bfb(acc[h][1][r]);
        }
    }
}

// GRU with fused contiguous gather-reduce (slots rp[a]..rp[a+1]).
__global__ __launch_bounds__(256) void gru_kernel(
    const float* __restrict__ atom, const unsigned short* __restrict__ msgbuf,
    const int* __restrict__ rp,
    const float* __restrict__ Wx, const float* __restrict__ Wh,
    const float* __restrict__ bx, const float* __restrict__ bh,
    unsigned short* __restrict__ Qh, unsigned short* __restrict__ Ql,
    unsigned short* __restrict__ Kh, unsigned short* __restrict__ Kl,
    unsigned short* __restrict__ Vth, unsigned short* __restrict__ Vtl)
{
    __shared__ float ag[8][33], at[8][33], hb[8][33];
    const int tid = threadIdx.x;
    const int r = tid >> 5, i = tid & 31;
    const int ha = blockIdx.x * 8 + r;
    const int h = ha >> 13;
    const int a = ha & 8191;
    {
        const int beg = rp[a];
        const int end = (a == NA - 1) ? NB : rp[a + 1];
        const unsigned short* mb = msgbuf + (size_t)h * NB * 32 + i;
        float av = 0.f;
        int x = beg;
        for (; x + 1 < end; x += 2) {
            float v0 = bf2f(mb[(size_t)x * 32]);
            float v1 = bf2f(mb[(size_t)(x + 1) * 32]);
            av += v0 + v1;
        }
        if (x < end) av += bf2f(mb[(size_t)x * 32]);
        ag[r][i] = av;
    }
    at[r][i] = atom[(size_t)a * 32 + i];
    __syncthreads();
    const float* wx = Wx + (size_t)h * 32 * 96;
    const float* wh = Wh + (size_t)h * 32 * 96;
    float x0 = bx[h*96 + i], x1 = bx[h*96 + 32 + i], x2 = bx[h*96 + 64 + i];
    float g0 = bh[h*96 + i], g1 = bh[h*96 + 32 + i], g2 = bh[h*96 + 64 + i];
    #pragma unroll 4
    for (int c = 0; c < 32; ++c) {
        float av = ag[r][c], hv = at[r][c];
        x0 += av * wx[c*96 + i]; x1 += av * wx[c*96 + 32 + i]; x2 += av * wx[c*96 + 64 + i];
        g0 += hv * wh[c*96 + i]; g1 += hv * wh[c*96 + 32 + i]; g2 += hv * wh[c*96 + 64 + i];
    }
    float z  = 1.f / (1.f + __expf(-(x0 + g0)));
    float rr = 1.f / (1.f + __expf(-(x1 + g1)));
    float hc = tanhf(x2 + rr * g2);
    float hn = z * at[r][i] + (1.f - z) * hc;
    if (h == 0) {
        float x = hn * 0.1767766952966369f;
        unsigned short hi = bfb(x);
        Qh[(size_t)a * 32 + i] = hi;
        Ql[(size_t)a * 32 + i] = bfb(x - bf2f(hi));
    } else if (h == 1) {
        unsigned short hi = bfb(hn);
        Kh[(size_t)a * 32 + i] = hi;
        Kl[(size_t)a * 32 + i] = bfb(hn - bf2f(hi));
    } else {
        hb[r][i] = hn;
        __syncthreads();
        const int a0 = blockIdx.x * 8 - 2 * NA;
        const int i2 = tid >> 3, a2 = tid & 7;
        float v = hb[a2][i2];
        unsigned short hi = bfb(v);
        Vth[(size_t)i2 * NA + a0 + a2] = hi;
        Vtl[(size_t)i2 * NA + a0 + a2] = bfb(v - bf2f(hi));
    }
}

// MFMA flash attention (R11): fixed-shift softmax, 32 q/wave, K/V double-
// buffered in LDS shared by 4 waves.
__global__ __launch_bounds__(256) void attn_mfma(
    const unsigned short* __restrict__ Qh, const unsigned short* __restrict__ Ql,
    const unsigned short* __restrict__ Kh, const unsigned short* __restrict__ Kl,
    const unsigned short* __restrict__ Vth, const unsigned short* __restrict__ Vtl,
    float* __restrict__ num, float* __restrict__ den)
{
    __shared__ unsigned short stg[2][4][32 * 40];
    __shared__ unsigned short pb[4][32 * 40];
    const int tid = threadIdx.x;
    const int wave = tid >> 6, lane = tid & 63;
    const int ln = lane & 15, quad = lane >> 4;
    const int sh = blockIdx.y;
    const int q0 = blockIdx.x * 128 + wave * 32;

    const int srow = lane >> 1, shalf = lane & 1;
    const unsigned short* sgbase = (wave == 0) ? Kh : (wave == 1) ? Kl
                                 : (wave == 2) ? Vth : Vtl;

    short8 qh0 = *(const short8*)(Qh + (size_t)(q0 + ln) * 32 + quad * 8);
    short8 ql0 = *(const short8*)(Ql + (size_t)(q0 + ln) * 32 + quad * 8);
    short8 qh1 = *(const short8*)(Qh + (size_t)(q0 + 16 + ln) * 32 + quad * 8);
    short8 ql1 = *(const short8*)(Ql + (size_t)(q0 + 16 + ln) * 32 + quad * 8);

    f4 a00 = {0,0,0,0}, a01 = {0,0,0,0}, a10 = {0,0,0,0}, a11 = {0,0,0,0};
    float l0 = 0.f, l1 = 0.f;
    unsigned short* pw = &pb[wave][0];
    const int kbeg = sh * (NA / NSHARD);

    {
        const unsigned short* gp = (wave < 2)
            ? sgbase + (size_t)(kbeg + srow) * 32 + shalf * 16
            : sgbase + (size_t)srow * NA + kbeg + shalf * 16;
        short8 v0 = *(const short8*)gp;
        short8 v1 = *(const short8*)(gp + 8);
        unsigned short* d = &stg[0][wave][srow * 40 + shalf * 16];
        *(short8*)d = v0;
        *(short8*)(d + 8) = v1;
    }
    int cur = 0;
    for (int it = 0; it < NIT; ++it) {
        __syncthreads();
        short8 nv0, nv1;
        const bool more = (it + 1 < NIT);
        if (more) {
            const int k1 = kbeg + (it + 1) * 32;
            const unsigned short* gp = (wave < 2)
                ? sgbase + (size_t)(k1 + srow) * 32 + shalf * 16
                : sgbase + (size_t)srow * NA + k1 + shalf * 16;
            nv0 = *(const short8*)gp;
            nv1 = *(const short8*)(gp + 8);
        }
        const unsigned short* KHt = &stg[cur][0][0];
        const unsigned short* KLt = &stg[cur][1][0];
        const unsigned short* VHt = &stg[cur][2][0];
        const unsigned short* VLt = &stg[cur][3][0];
        short8 kh0 = *(const short8*)&KHt[ln * 40 + quad * 8];
        short8 kh1 = *(const short8*)&KHt[(16 + ln) * 40 + quad * 8];
        short8 kl0 = *(const short8*)&KLt[ln * 40 + quad * 8];
        short8 kl1 = *(const short8*)&KLt[(16 + ln) * 40 + quad * 8];

        f4 s00 = {0,0,0,0}, s01 = {0,0,0,0}, s10 = {0,0,0,0}, s11 = {0,0,0,0};
        s00 = __builtin_amdgcn_mfma_f32_16x16x32_bf16(kl0, qh0, s00, 0, 0, 0);
        s00 = __builtin_amdgcn_mfma_f32_16x16x32_bf16(kh0, ql0, s00, 0, 0, 0);
        s00 = __builtin_amdgcn_mfma_f32_16x16x32_bf16(kh0, qh0, s00, 0, 0, 0);
        s01 = __builtin_amdgcn_mfma_f32_16x16x32_bf16(kl0, qh1, s01, 0, 0, 0);
        s01 = __builtin_amdgcn_mfma_f32_16x16x32_bf16(kh0, ql1, s01, 0, 0, 0);
        s01 = __builtin_amdgcn_mfma_f32_16x16x32_bf16(kh0, qh1, s01, 0, 0, 0);
        s10 = __builtin_amdgcn_mfma_f32_16x16x32_bf16(kl1, qh0, s10, 0, 0, 0);
        s10 = __builtin_amdgcn_mfma_f32_16x16x32_bf16(kh1, ql0, s10, 0, 0, 0);
        s10 = __builtin_amdgcn_mfma_f32_16x16x32_bf16(kh1, qh0, s10, 0, 0, 0);
        s11 = __builtin_amdgcn_mfma_f32_16x16x32_bf16(kl1, qh1, s11, 0, 0, 0);
        s11 = __builtin_amdgcn_mfma_f32_16x16x32_bf16(kh1, ql1, s11, 0, 0, 0);
        s11 = __builtin_amdgcn_mfma_f32_16x16x32_bf16(kh1, qh1, s11, 0, 0, 0);

        {
            float e0 = __expf(s00[0]-64.f), e1 = __expf(s00[1]-64.f),
                  e2 = __expf(s00[2]-64.f), e3 = __expf(s00[3]-64.f);
            l0 += (e0+e1)+(e2+e3);
            *(uint2v*)&pw[ln*40 + quad*4] = uint2v{pk2(e0,e1), pk2(e2,e3)};
            e0 = __expf(s10[0]-64.f); e1 = __expf(s10[1]-64.f);
            e2 = __expf(s10[2]-64.f); e3 = __expf(s10[3]-64.f);
            l0 += (e0+e1)+(e2+e3);
            *(uint2v*)&pw[ln*40 + 16 + quad*4] = uint2v{pk2(e0,e1), pk2(e2,e3)};
            e0 = __expf(s01[0]-64.f); e1 = __expf(s01[1]-64.f);
            e2 = __expf(s01[2]-64.f); e3 = __expf(s01[3]-64.f);
            l1 += (e0+e1)+(e2+e3);
            *(uint2v*)&pw[(16+ln)*40 + quad*4] = uint2v{pk2(e0,e1), pk2(e2,e3)};
            e0 = __expf(s11[0]-64.f); e1 = __expf(s11[1]-64.f);
            e2 = __expf(s11[2]-64.f); e3 = __expf(s11[3]-64.f);
            l1 += (e0+e1)+(e2+e3);
            *(uint2v*)&pw[(16+ln)*40 + 16 + quad*4] = uint2v{pk2(e0,e1), pk2(e2,e3)};
        }
        short8 pa0 = *(const short8*)&pw[ln*40 + quad*8];
        short8 pa1 = *(const short8*)&pw[(16+ln)*40 + quad*8];

        short8 vh0 = *(const short8*)&VHt[ln * 40 + quad * 8];
        short8 vh1 = *(const short8*)&VHt[(16 + ln) * 40 + quad * 8];
        short8 vl0 = *(const short8*)&VLt[ln * 40 + quad * 8];
        short8 vl1 = *(const short8*)&VLt[(16 + ln) * 40 + quad * 8];

        a00 = __builtin_amdgcn_mfma_f32_16x16x32_bf16(pa0, vl0, a00, 0, 0, 0);
        a00 = __builtin_amdgcn_mfma_f32_16x16x32_bf16(pa0, vh0, a00, 0, 0, 0);
        a01 = __builtin_amdgcn_mfma_f32_16x16x32_bf16(pa0, vl1, a01, 0, 0, 0);
        a01 = __builtin_amdgcn_mfma_f32_16x16x32_bf16(pa0, vh1, a01, 0, 0, 0);
        a10 = __builtin_amdgcn_mfma_f32_16x16x32_bf16(pa1, vl0, a10, 0, 0, 0);
        a10 = __builtin_amdgcn_mfma_f32_16x16x32_bf16(pa1, vh0, a10, 0, 0, 0);
        a11 = __builtin_amdgcn_mfma_f32_16x16x32_bf16(pa1, vl1, a11, 0, 0, 0);
        a11 = __builtin_amdgcn_mfma_f32_16x16x32_bf16(pa1, vh1, a11, 0, 0, 0);

        if (more) {
            unsigned short* d = &stg[cur ^ 1][wave][srow * 40 + shalf * 16];
            *(short8*)d = nv0;
            *(short8*)(d + 8) = nv1;
        }
        cur ^= 1;
    }
    l0 += __shfl_xor(l0, 16); l0 += __shfl_xor(l0, 32);
    l1 += __shfl_xor(l1, 16); l1 += __shfl_xor(l1, 32);

    #pragma unroll
    for (int r = 0; r < 4; ++r) {
        const int row0 = q0 + quad * 4 + r;
        float* np = num + ((size_t)sh * NA + row0) * 32;
        np[ln] = a00[r]; np[16 + ln] = a01[r];
        float* nq = num + ((size_t)sh * NA + row0 + 16) * 32;
        nq[ln] = a10[r]; nq[16 + ln] = a11[r];
    }
    if (quad == 0) {
        den[(size_t)sh * NA + q0 + ln]      = l0;
        den[(size_t)sh * NA + q0 + 16 + ln] = l1;
    }
}

__global__ __launch_bounds__(256) void merge_kernel(const float* __restrict__ num,
                                                    const float* __restrict__ den,
                                                    float* __restrict__ out)
{
    const int tid = threadIdx.x;
    const int r = tid >> 5, c = tid & 31;
    const int q = blockIdx.x * 8 + r;
    float ds = 0.f, ns = 0.f;
    #pragma unroll
    for (int sh = 0; sh < NSHARD; ++sh) {
        ns += num[((size_t)sh * NA + q) * 32 + c];
        ds += den[(size_t)sh * NA + q];
    }
    out[(size_t)q * 32 + c] = ns / ds;
}

extern "C" void kernel_launch(void* const* d_in, const int* in_sizes, int n_in,
                              void* d_out, int out_size, void* d_ws, size_t ws_size,
                              hipStream_t stream)
{
    const float* atom  = (const float*)d_in[0];
    const float* bond  = (const float*)d_in[1];
    const float* state = (const float*)d_in[2];
    const float* We    = (const float*)d_in[3];
    const float* be    = (const float*)d_in[4];
    const float* Wx    = (const float*)d_in[5];
    const float* Wh    = (const float*)d_in[6];
    const float* bx    = (const float*)d_in[7];
    const float* bh    = (const float*)d_in[8];
    const int*   pair  = (const int*)d_in[9];
    const int*   bg    = (const int*)d_in[11];
    float* ws = (float*)d_ws;
    unsigned short* Bh  = (unsigned short*)(ws + OFF_BH);
    unsigned short* Vb  = (unsigned short*)(ws + OFF_VB);
    int* cnt   = (int*)(ws + OFF_CNT);
    int* cur   = (int*)(ws + OFF_CUR);
    int* rp    = (int*)(ws + OFF_RP);
    int* islot = (int*)(ws + OFF_ISLOT);
    unsigned short* Qh  = (unsigned short*)(ws + OFF_QH);
    unsigned short* Ql  = (unsigned short*)(ws + OFF_QL);
    unsigned short* Kh  = (unsigned short*)(ws + OFF_KH);
    unsigned short* Kl  = (unsigned short*)(ws + OFF_KL);
    unsigned short* Vth = (unsigned short*)(ws + OFF_VTH);
    unsigned short* Vtl = (unsigned short*)(ws + OFF_VTL);
    unsigned short* msgbuf = (unsigned short*)(ws + OFF_MSG);
    float* num = ws + OFF_NUM;
    float* den = ws + OFF_DEN;
    float* out = (float*)d_out;

    hipMemsetAsync(cnt, 0, NA * sizeof(int), stream);
    prep_all<<<512, 256, 0, stream>>>(We, state, be, pair, Bh, Vb, cnt);
    scan_kernel<<<1, 256, 0, stream>>>(cnt, cur, rp);
    scatter_kernel<<<512, 256, 0, stream>>>(pair, cur, islot);
    msg_mfma<<<NB / 64, 256, 0, stream>>>(atom, bond, Bh, Vb, pair, bg, islot, msgbuf);
    gru_kernel<<<3 * NA / 8, 256, 0, stream>>>(atom, msgbuf, rp, Wx, Wh, bx, bh,
                                               Qh, Ql, Kh, Kl, Vth, Vtl);
    attn_mfma<<<dim3(NA / 128, NSHARD), 256, 0, stream>>>(Qh, Ql, Kh, Kl, Vth, Vtl, num, den);
    merge_kernel<<<NA / 8, 256, 0, stream>>>(num, den, out);
}

// Round 13
// 206.070 us; speedup vs baseline: 1.2678x; 1.2678x over previous
//
#include <hip/hip_runtime.h>
#include <hip/hip_bf16.h>
#include <math.h>

#define NA 8192
#define NB 131072
#define NG 16
#define NSHARD 16
#define NIT 16            // (NA/NSHARD)/32

// workspace layout (float offsets)
#define OFF_BH    0u          // 3*32*1024 bf16 = 49152 f
#define OFF_VB    49152u      // 24576 f
#define OFF_CNT   73728u      // 8192 int
#define OFF_CUR   81920u      // 8192 int
#define OFF_RP    90112u      // 8192 int
#define OFF_ISLOT 98304u      // 131072 int (edge -> dst-sorted slot)
#define OFF_QH    229376u     // 8192*32 bf16 = 131072 f each
#define OFF_QL    360448u
#define OFF_KH    491520u
#define OFF_KL    622592u
#define OFF_VTH   753664u
#define OFF_VTL   884736u
#define OFF_MSG   1015808u    // 3*131072*32 bf16 = 6291456 f
#define OFF_NUM   1015808u    // ALIAS of MSG (msgbuf dead before attn writes num)
#define OFF_DEN   7307264u    // 131072 f  (end ~29.8 MB)

typedef __attribute__((ext_vector_type(8))) short short8;
typedef __attribute__((ext_vector_type(4))) float f4;
typedef __attribute__((ext_vector_type(2))) float f2;
typedef __attribute__((ext_vector_type(2))) unsigned int uint2v;

__device__ inline unsigned short bfb(float x) {
    __hip_bfloat16 b = __float2bfloat16(x);   // RNE
    return reinterpret_cast<unsigned short&>(b);
}
__device__ inline float bf2f(unsigned short u) {
    unsigned int x = ((unsigned int)u) << 16;
    return __uint_as_float(x);
}
__device__ inline unsigned int pk2(float x, float y) {
    __hip_bfloat162 t = __float22bfloat162_rn(make_float2(x, y));
    union { __hip_bfloat162 b; unsigned int u; } cv;
    cv.b = t;
    return cv.u;
}

// Fused: edge-dst histogram (all 512 blocks) + prep_bh (bid<96) + prep_v (96<=bid<144)
__global__ __launch_bounds__(256) void prep_all(
    const float* __restrict__ We, const float* __restrict__ state,
    const float* __restrict__ be, const int* __restrict__ pair,
    unsigned short* __restrict__ Bh, unsigned short* __restrict__ Vb,
    int* __restrict__ cnt)
{
    const int bid = blockIdx.x, tid = threadIdx.x;
    const int e = bid * 256 + tid;
    atomicAdd(&cnt[pair[2 * e]], 1);
    if (bid < 96) {
        int idx = bid * 256 + tid;
        int hc = idx >> 8;
        int n4 = (idx & 255) * 4;
        const float4 v = *(const float4*)(We + ((size_t)((hc >> 5) * 64 + (hc & 31))) * 1024 + n4);
        unsigned short* d = Bh + (size_t)hc * 1024 + n4;
        d[0] = bfb(v.x); d[1] = bfb(v.y); d[2] = bfb(v.z); d[3] = bfb(v.w);
    } else if (bid < 144) {
        int b2 = bid - 96;
        int h = b2 >> 4, g = b2 & 15;
        const float* st = state + g * 32;
        const float* W  = We + ((size_t)h * 64 + 32) * 1024;
        const float* bb = be + (size_t)h * 1024;
        int n = tid * 4;
        float4 acc = *(const float4*)(bb + n);
        for (int c = 0; c < 32; ++c) {
            float s = st[c];
            const float4 w = *(const float4*)(W + c * 1024 + n);
            acc.x += s * w.x; acc.y += s * w.y; acc.z += s * w.z; acc.w += s * w.w;
        }
        unsigned short* d = Vb + ((size_t)h * 16 + g) * 1024 + n;
        d[0] = bfb(acc.x); d[1] = bfb(acc.y); d[2] = bfb(acc.z); d[3] = bfb(acc.w);
    }
}

// Exclusive scan of 8192 counts -> cur (scatter cursors) + rp (rowptr)
__global__ __launch_bounds__(256) void scan_kernel(const int* __restrict__ cnt,
                                                   int* __restrict__ cur,
                                                   int* __restrict__ rp)
{
    __shared__ int part[256];
    const int t = threadIdx.x;
    const int base = t * 32;
    int loc[32];
    int s = 0;
    #pragma unroll
    for (int k = 0; k < 32; ++k) { loc[k] = cnt[base + k]; s += loc[k]; }
    part[t] = s;
    __syncthreads();
    for (int off = 1; off < 256; off <<= 1) {
        int add = (t >= off) ? part[t - off] : 0;
        __syncthreads();
        part[t] += add;
        __syncthreads();
    }
    int excl = part[t] - s;
    #pragma unroll
    for (int k = 0; k < 32; ++k) {
        cur[base + k] = excl; rp[base + k] = excl; excl += loc[k];
    }
}

// islot[e] = dst-sorted slot of edge e
__global__ __launch_bounds__(256) void scatter_kernel(const int* __restrict__ pair,
                                                      int* __restrict__ cur,
                                                      int* __restrict__ islot)
{
    const int e = blockIdx.x * 256 + threadIdx.x;
    const int d = pair[2 * e];
    islot[e] = atomicAdd(&cur[d], 1);
}

// MFMA edge-message GEMM: 3 heads fused, B-tiles double-buffered through LDS
// (shared by 4 waves; K-loop has ZERO global loads). Wave = 2 M-tiles x 3 heads
// x 2 N-tiles = 12 MFMA/c-step; A-build once per M-tile per step.
__global__ __launch_bounds__(256) void msg_mfma(
    const float* __restrict__ atom, const float* __restrict__ bond,
    const unsigned short* __restrict__ Bh, const unsigned short* __restrict__ Vb,
    const int* __restrict__ pair, const int* __restrict__ bg,
    const int* __restrict__ islot, unsigned short* __restrict__ msgbuf)
{
    __shared__ float bl[128 * 36];
    __shared__ unsigned short Bs[2][3 * 1024];   // [buf][head*1024 + n]
    __shared__ int gmm[2];
    const int tid = threadIdx.x;
    const int e0 = blockIdx.x * 128;
    for (int x = tid; x < 1024; x += 256) {
        int e = x >> 3, c4 = (x & 7) << 2;
        float4 v = *(const float4*)(bond + (size_t)(e0 + e) * 32 + c4);
        float* d = &bl[e * 36 + c4];
        d[0] = v.x; d[1] = v.y; d[2] = v.z; d[3] = v.w;
    }
    if (tid == 0) { gmm[0] = bg[e0]; gmm[1] = bg[e0 + 127]; }

    const int wave = tid >> 6, lane = tid & 63;
    const int ln = lane & 15, quad = lane >> 4;
    const int em0 = e0 + wave * 32 + ln;
    const int em1 = em0 + 16;
    const int src0 = pair[2 * em0 + 1], src1 = pair[2 * em1 + 1];
    const int gv0 = bg[em0], gv1 = bg[em1];
    f2 n0p[4], n1p[4];
    {
        const float* p0 = atom + (size_t)src0 * 32 + quad * 8;
        const float* p1 = atom + (size_t)src1 * 32 + quad * 8;
        float4 a = *(const float4*)p0, b = *(const float4*)(p0 + 4);
        n0p[0] = f2{a.x, a.y}; n0p[1] = f2{a.z, a.w};
        n0p[2] = f2{b.x, b.y}; n0p[3] = f2{b.z, b.w};
        float4 c = *(const float4*)p1, d = *(const float4*)(p1 + 4);
        n1p[0] = f2{c.x, c.y}; n1p[1] = f2{c.z, c.w};
        n1p[2] = f2{d.x, d.y}; n1p[3] = f2{d.z, d.w};
    }
    // staging roles: slot s in [0,384): h = s>>7, n8 = s&127 (one short8 each)
    const int s0slot = tid, s1slot = tid + 256;
    const bool has1 = (s1slot < 384);
    // preload c=0 into buf 0
    {
        short8 v0 = *(const short8*)(Bh + ((size_t)((s0slot >> 7) * 32)) * 1024 + (s0slot & 127) * 8);
        *(short8*)&Bs[0][s0slot * 8] = v0;
        if (has1) {
            short8 v1 = *(const short8*)(Bh + ((size_t)((s1slot >> 7) * 32)) * 1024 + (s1slot & 127) * 8);
            *(short8*)&Bs[0][s1slot * 8] = v1;
        }
    }
    __syncthreads();

    f4 acc[2][3][2];
    #pragma unroll
    for (int mt = 0; mt < 2; ++mt)
        #pragma unroll
        for (int h = 0; h < 3; ++h) {
            acc[mt][h][0] = f4{0,0,0,0}; acc[mt][h][1] = f4{0,0,0,0};
        }

    const int bo0 = (wave * 32 + ln) * 36;
    const int bo1 = bo0 + 16 * 36;
    const int boff = ln * 32 + quad * 8;
    int cur = 0;
    for (int c4 = 0; c4 < 32; c4 += 4) {
        const f4 cv0 = *(const f4*)&bl[bo0 + c4];   // bl is static: no barrier hazard
        const f4 cv1 = *(const f4*)&bl[bo1 + c4];
        #pragma unroll
        for (int u = 0; u < 4; ++u) {
            const int c = c4 + u;
            __syncthreads();
            short8 nv0, nv1;
            const bool more = (c < 31);
            if (more) {   // prefetch c+1 (global -> regs; no wait until ds_write)
                nv0 = *(const short8*)(Bh + ((size_t)((s0slot >> 7) * 32 + c + 1)) * 1024 + (s0slot & 127) * 8);
                if (has1)
                    nv1 = *(const short8*)(Bh + ((size_t)((s1slot >> 7) * 32 + c + 1)) * 1024 + (s1slot & 127) * 8);
            }
            const float c0 = cv0[u], c1 = cv1[u];
            union { unsigned int u4[4]; short8 s; } A0, A1;
            #pragma unroll
            for (int q2 = 0; q2 < 4; ++q2) {
                f2 p0 = c0 * n0p[q2];
                f2 p1 = c1 * n1p[q2];
                A0.u4[q2] = pk2(p0.x, p0.y);
                A1.u4[q2] = pk2(p1.x, p1.y);
            }
            #pragma unroll
            for (int h = 0; h < 3; ++h) {
                short8 b0 = *(const short8*)&Bs[cur][h * 1024 + boff];
                short8 b1 = *(const short8*)&Bs[cur][h * 1024 + 512 + boff];
                acc[0][h][0] = __builtin_amdgcn_mfma_f32_16x16x32_bf16(A0.s, b0, acc[0][h][0], 0, 0, 0);
                acc[0][h][1] = __builtin_amdgcn_mfma_f32_16x16x32_bf16(A0.s, b1, acc[0][h][1], 0, 0, 0);
                acc[1][h][0] = __builtin_amdgcn_mfma_f32_16x16x32_bf16(A1.s, b0, acc[1][h][0], 0, 0, 0);
                acc[1][h][1] = __builtin_amdgcn_mfma_f32_16x16x32_bf16(A1.s, b1, acc[1][h][1], 0, 0, 0);
            }
            if (more) {
                *(short8*)&Bs[cur ^ 1][s0slot * 8] = nv0;
                if (has1) *(short8*)&Bs[cur ^ 1][s1slot * 8] = nv1;
            }
            cur ^= 1;
        }
    }
    // state/V term (bg sorted: 1-2 g's), B from global (tiny)
    union { unsigned int u4[4]; short8 s; } NB0, NB1;
    #pragma unroll
    for (int q2 = 0; q2 < 4; ++q2) {
        NB0.u4[q2] = pk2(n0p[q2].x, n0p[q2].y);
        NB1.u4[q2] = pk2(n1p[q2].x, n1p[q2].y);
    }
    const short8 zz = {0,0,0,0,0,0,0,0};
    const int gmin = gmm[0], gmax = gmm[1];
    for (int g = gmin; g <= gmax; ++g) {
        short8 a0 = (gv0 == g) ? NB0.s : zz;
        short8 a1 = (gv1 == g) ? NB1.s : zz;
        #pragma unroll
        for (int h = 0; h < 3; ++h) {
            const unsigned short* vp = Vb + ((size_t)h * 16 + g) * 1024 + boff;
            short8 b0 = *(const short8*)vp;
            short8 b1 = *(const short8*)(vp + 512);
            acc[0][h][0] = __builtin_amdgcn_mfma_f32_16x16x32_bf16(a0, b0, acc[0][h][0], 0, 0, 0);
            acc[0][h][1] = __builtin_amdgcn_mfma_f32_16x16x32_bf16(a0, b1, acc[0][h][1], 0, 0, 0);
            acc[1][h][0] = __builtin_amdgcn_mfma_f32_16x16x32_bf16(a1, b0, acc[1][h][0], 0, 0, 0);
            acc[1][h][1] = __builtin_amdgcn_mfma_f32_16x16x32_bf16(a1, b1, acc[1][h][1], 0, 0, 0);
        }
    }
    // epilogue: dst-sorted streaming stores
    const int ebA = e0 + wave * 32 + quad * 4;
    int4 sA = *(const int4*)(islot + ebA);
    int4 sB = *(const int4*)(islot + ebA + 16);
    const int slA[4] = {sA.x, sA.y, sA.z, sA.w};
    const int slB[4] = {sB.x, sB.y, sB.z, sB.w};
    #pragma unroll
    for (int r = 0; r < 4; ++r) {
        #pragma unroll
        for (int h = 0; h < 3; ++h) {
            unsigned short* dA = msgbuf + ((size_t)h * NB + slA[r]) * 32;
            unsigned short* dB = msgbuf + ((size_t)h * NB + slB[r]) * 32;
            dA[ln]      = bfb(acc[0][h][0][r]);
            dA[16 + ln] = bfb(acc[0][h][1][r]);
            dB[ln]      = bfb(acc[1][h][0][r]);
            dB[16 + ln] = bfb(acc[1][h][1][r]);
        }
    }
}

// GRU with fused contiguous gather-reduce (slots rp[a]..rp[a+1]).
__global__ __launch_bounds__(256) void gru_kernel(
    const float* __restrict__ atom, const unsigned short* __restrict__ msgbuf,
    const int* __restrict__ rp,
    const float* __restrict__ Wx, const float* __restrict__ Wh,
    const float* __restrict__ bx, const float* __restrict__ bh,
    unsigned short* __restrict__ Qh, unsigned short* __restrict__ Ql,
    unsigned short* __restrict__ Kh, unsigned short* __restrict__ Kl,
    unsigned short* __restrict__ Vth, unsigned short* __restrict__ Vtl)
{
    __shared__ float ag[8][33], at[8][33], hb[8][33];
    const int tid = threadIdx.x;
    const int r = tid >> 5, i = tid & 31;
    const int ha = blockIdx.x * 8 + r;
    const int h = ha >> 13;
    const int a = ha & 8191;
    {
        const int beg = rp[a];
        const int end = (a == NA - 1) ? NB : rp[a + 1];
        const unsigned short* mb = msgbuf + (size_t)h * NB * 32 + i;
        float av = 0.f;
        int x = beg;
        for (; x + 1 < end; x += 2) {
            float v0 = bf2f(mb[(size_t)x * 32]);
            float v1 = bf2f(mb[(size_t)(x + 1) * 32]);
            av += v0 + v1;
        }
        if (x < end) av += bf2f(mb[(size_t)x * 32]);
        ag[r][i] = av;
    }
    at[r][i] = atom[(size_t)a * 32 + i];
    __syncthreads();
    const float* wx = Wx + (size_t)h * 32 * 96;
    const float* wh = Wh + (size_t)h * 32 * 96;
    float x0 = bx[h*96 + i], x1 = bx[h*96 + 32 + i], x2 = bx[h*96 + 64 + i];
    float g0 = bh[h*96 + i], g1 = bh[h*96 + 32 + i], g2 = bh[h*96 + 64 + i];
    #pragma unroll 4
    for (int c = 0; c < 32; ++c) {
        float av = ag[r][c], hv = at[r][c];
        x0 += av * wx[c*96 + i]; x1 += av * wx[c*96 + 32 + i]; x2 += av * wx[c*96 + 64 + i];
        g0 += hv * wh[c*96 + i]; g1 += hv * wh[c*96 + 32 + i]; g2 += hv * wh[c*96 + 64 + i];
    }
    float z  = 1.f / (1.f + __expf(-(x0 + g0)));
    float rr = 1.f / (1.f + __expf(-(x1 + g1)));
    float hc = tanhf(x2 + rr * g2);
    float hn = z * at[r][i] + (1.f - z) * hc;
    if (h == 0) {
        float x = hn * 0.1767766952966369f;
        unsigned short hi = bfb(x);
        Qh[(size_t)a * 32 + i] = hi;
        Ql[(size_t)a * 32 + i] = bfb(x - bf2f(hi));
    } else if (h == 1) {
        unsigned short hi = bfb(hn);
        Kh[(size_t)a * 32 + i] = hi;
        Kl[(size_t)a * 32 + i] = bfb(hn - bf2f(hi));
    } else {
        hb[r][i] = hn;
        __syncthreads();
        const int a0 = blockIdx.x * 8 - 2 * NA;
        const int i2 = tid >> 3, a2 = tid & 7;
        float v = hb[a2][i2];
        unsigned short hi = bfb(v);
        Vth[(size_t)i2 * NA + a0 + a2] = hi;
        Vtl[(size_t)i2 * NA + a0 + a2] = bfb(v - bf2f(hi));
    }
}

// MFMA flash attention (R11): fixed-shift softmax, 32 q/wave, K/V double-
// buffered in LDS shared by 4 waves.
__global__ __launch_bounds__(256) void attn_mfma(
    const unsigned short* __restrict__ Qh, const unsigned short* __restrict__ Ql,
    const unsigned short* __restrict__ Kh, const unsigned short* __restrict__ Kl,
    const unsigned short* __restrict__ Vth, const unsigned short* __restrict__ Vtl,
    float* __restrict__ num, float* __restrict__ den)
{
    __shared__ unsigned short stg[2][4][32 * 40];
    __shared__ unsigned short pb[4][32 * 40];
    const int tid = threadIdx.x;
    const int wave = tid >> 6, lane = tid & 63;
    const int ln = lane & 15, quad = lane >> 4;
    const int sh = blockIdx.y;
    const int q0 = blockIdx.x * 128 + wave * 32;

    const int srow = lane >> 1, shalf = lane & 1;
    const unsigned short* sgbase = (wave == 0) ? Kh : (wave == 1) ? Kl
                                 : (wave == 2) ? Vth : Vtl;

    short8 qh0 = *(const short8*)(Qh + (size_t)(q0 + ln) * 32 + quad * 8);
    short8 ql0 = *(const short8*)(Ql + (size_t)(q0 + ln) * 32 + quad * 8);
    short8 qh1 = *(const short8*)(Qh + (size_t)(q0 + 16 + ln) * 32 + quad * 8);
    short8 ql1 = *(const short8*)(Ql + (size_t)(q0 + 16 + ln) * 32 + quad * 8);

    f4 a00 = {0,0,0,0}, a01 = {0,0,0,0}, a10 = {0,0,0,0}, a11 = {0,0,0,0};
    float l0 = 0.f, l1 = 0.f;
    unsigned short* pw = &pb[wave][0];
    const int kbeg = sh * (NA / NSHARD);

    {
        const unsigned short* gp = (wave < 2)
            ? sgbase + (size_t)(kbeg + srow) * 32 + shalf * 16
            : sgbase + (size_t)srow * NA + kbeg + shalf * 16;
        short8 v0 = *(const short8*)gp;
        short8 v1 = *(const short8*)(gp + 8);
        unsigned short* d = &stg[0][wave][srow * 40 + shalf * 16];
        *(short8*)d = v0;
        *(short8*)(d + 8) = v1;
    }
    int cur = 0;
    for (int it = 0; it < NIT; ++it) {
        __syncthreads();
        short8 nv0, nv1;
        const bool more = (it + 1 < NIT);
        if (more) {
            const int k1 = kbeg + (it + 1) * 32;
            const unsigned short* gp = (wave < 2)
                ? sgbase + (size_t)(k1 + srow) * 32 + shalf * 16
                : sgbase + (size_t)srow * NA + k1 + shalf * 16;
            nv0 = *(const short8*)gp;
            nv1 = *(const short8*)(gp + 8);
        }
        const unsigned short* KHt = &stg[cur][0][0];
        const unsigned short* KLt = &stg[cur][1][0];
        const unsigned short* VHt = &stg[cur][2][0];
        const unsigned short* VLt = &stg[cur][3][0];
        short8 kh0 = *(const short8*)&KHt[ln * 40 + quad * 8];
        short8 kh1 = *(const short8*)&KHt[(16 + ln) * 40 + quad * 8];
        short8 kl0 = *(const short8*)&KLt[ln * 40 + quad * 8];
        short8 kl1 = *(const short8*)&KLt[(16 + ln) * 40 + quad * 8];

        f4 s00 = {0,0,0,0}, s01 = {0,0,0,0}, s10 = {0,0,0,0}, s11 = {0,0,0,0};
        s00 = __builtin_amdgcn_mfma_f32_16x16x32_bf16(kl0, qh0, s00, 0, 0, 0);
        s00 = __builtin_amdgcn_mfma_f32_16x16x32_bf16(kh0, ql0, s00, 0, 0, 0);
        s00 = __builtin_amdgcn_mfma_f32_16x16x32_bf16(kh0, qh0, s00, 0, 0, 0);
        s01 = __builtin_amdgcn_mfma_f32_16x16x32_bf16(kl0, qh1, s01, 0, 0, 0);
        s01 = __builtin_amdgcn_mfma_f32_16x16x32_bf16(kh0, ql1, s01, 0, 0, 0);
        s01 = __builtin_amdgcn_mfma_f32_16x16x32_bf16(kh0, qh1, s01, 0, 0, 0);
        s10 = __builtin_amdgcn_mfma_f32_16x16x32_bf16(kl1, qh0, s10, 0, 0, 0);
        s10 = __builtin_amdgcn_mfma_f32_16x16x32_bf16(kh1, ql0, s10, 0, 0, 0);
        s10 = __builtin_amdgcn_mfma_f32_16x16x32_bf16(kh1, qh0, s10, 0, 0, 0);
        s11 = __builtin_amdgcn_mfma_f32_16x16x32_bf16(kl1, qh1, s11, 0, 0, 0);
        s11 = __builtin_amdgcn_mfma_f32_16x16x32_bf16(kh1, ql1, s11, 0, 0, 0);
        s11 = __builtin_amdgcn_mfma_f32_16x16x32_bf16(kh1, qh1, s11, 0, 0, 0);

        {
            float e0 = __expf(s00[0]-64.f), e1 = __expf(s00[1]-64.f),
                  e2 = __expf(s00[2]-64.f), e3 = __expf(s00[3]-64.f);
            l0 += (e0+e1)+(e2+e3);
            *(uint2v*)&pw[ln*40 + quad*4] = uint2v{pk2(e0,e1), pk2(e2,e3)};
            e0 = __expf(s10[0]-64.f); e1 = __expf(s10[1]-64.f);
            e2 = __expf(s10[2]-64.f); e3 = __expf(s10[3]-64.f);
            l0 += (e0+e1)+(e2+e3);
            *(uint2v*)&pw[ln*40 + 16 + quad*4] = uint2v{pk2(e0,e1), pk2(e2,e3)};
            e0 = __expf(s01[0]-64.f); e1 = __expf(s01[1]-64.f);
            e2 = __expf(s01[2]-64.f); e3 = __expf(s01[3]-64.f);
            l1 += (e0+e1)+(e2+e3);
            *(uint2v*)&pw[(16+ln)*40 + quad*4] = uint2v{pk2(e0,e1), pk2(e2,e3)};
            e0 = __expf(s11[0]-64.f); e1 = __expf(s11[1]-64.f);
            e2 = __expf(s11[2]-64.f); e3 = __expf(s11[3]-64.f);
            l1 += (e0+e1)+(e2+e3);
            *(uint2v*)&pw[(16+ln)*40 + 16 + quad*4] = uint2v{pk2(e0,e1), pk2(e2,e3)};
        }
        short8 pa0 = *(const short8*)&pw[ln*40 + quad*8];
        short8 pa1 = *(const short8*)&pw[(16+ln)*40 + quad*8];

        short8 vh0 = *(const short8*)&VHt[ln * 40 + quad * 8];
        short8 vh1 = *(const short8*)&VHt[(16 + ln) * 40 + quad * 8];
        short8 vl0 = *(const short8*)&VLt[ln * 40 + quad * 8];
        short8 vl1 = *(const short8*)&VLt[(16 + ln) * 40 + quad * 8];

        a00 = __builtin_amdgcn_mfma_f32_16x16x32_bf16(pa0, vl0, a00, 0, 0, 0);
        a00 = __builtin_amdgcn_mfma_f32_16x16x32_bf16(pa0, vh0, a00, 0, 0, 0);
        a01 = __builtin_amdgcn_mfma_f32_16x16x32_bf16(pa0, vl1, a01, 0, 0, 0);
        a01 = __builtin_amdgcn_mfma_f32_16x16x32_bf16(pa0, vh1, a01, 0, 0, 0);
        a10 = __builtin_amdgcn_mfma_f32_16x16x32_bf16(pa1, vl0, a10, 0, 0, 0);
        a10 = __builtin_amdgcn_mfma_f32_16x16x32_bf16(pa1, vh0, a10, 0, 0, 0);
        a11 = __builtin_amdgcn_mfma_f32_16x16x32_bf16(pa1, vl1, a11, 0, 0, 0);
        a11 = __builtin_amdgcn_mfma_f32_16x16x32_bf16(pa1, vh1, a11, 0, 0, 0);

        if (more) {
            unsigned short* d = &stg[cur ^ 1][wave][srow * 40 + shalf * 16];
            *(short8*)d = nv0;
            *(short8*)(d + 8) = nv1;
        }
        cur ^= 1;
    }
    l0 += __shfl_xor(l0, 16); l0 += __shfl_xor(l0, 32);
    l1 += __shfl_xor(l1, 16); l1 += __shfl_xor(l1, 32);

    #pragma unroll
    for (int r = 0; r < 4; ++r) {
        const int row0 = q0 + quad * 4 + r;
        float* np = num + ((size_t)sh * NA + row0) * 32;
        np[ln] = a00[r]; np[16 + ln] = a01[r];
        float* nq = num + ((size_t)sh * NA + row0 + 16) * 32;
        nq[ln] = a10[r]; nq[16 + ln] = a11[r];
    }
    if (quad == 0) {
        den[(size_t)sh * NA + q0 + ln]      = l0;
        den[(size_t)sh * NA + q0 + 16 + ln] = l1;
    }
}

__global__ __launch_bounds__(256) void merge_kernel(const float* __restrict__ num,
                                                    const float* __restrict__ den,
                                                    float* __restrict__ out)
{
    const int tid = threadIdx.x;
    const int r = tid >> 5, c = tid & 31;
    const int q = blockIdx.x * 8 + r;
    float ds = 0.f, ns = 0.f;
    #pragma unroll
    for (int sh = 0; sh < NSHARD; ++sh) {
        ns += num[((size_t)sh * NA + q) * 32 + c];
        ds += den[(size_t)sh * NA + q];
    }
    out[(size_t)q * 32 + c] = ns / ds;
}

extern "C" void kernel_launch(void* const* d_in, const int* in_sizes, int n_in,
                              void* d_out, int out_size, void* d_ws, size_t ws_size,
                              hipStream_t stream)
{
    const float* atom  = (const float*)d_in[0];
    const float* bond  = (const float*)d_in[1];
    const float* state = (const float*)d_in[2];
    const float* We    = (const float*)d_in[3];
    const float* be    = (const float*)d_in[4];
    const float* Wx    = (const float*)d_in[5];
    const float* Wh    = (const float*)d_in[6];
    const float* bx    = (const float*)d_in[7];
    const float* bh    = (const float*)d_in[8];
    const int*   pair  = (const int*)d_in[9];
    const int*   bg    = (const int*)d_in[11];
    float* ws = (float*)d_ws;
    unsigned short* Bh  = (unsigned short*)(ws + OFF_BH);
    unsigned short* Vb  = (unsigned short*)(ws + OFF_VB);
    int* cnt   = (int*)(ws + OFF_CNT);
    int* cur   = (int*)(ws + OFF_CUR);
    int* rp    = (int*)(ws + OFF_RP);
    int* islot = (int*)(ws + OFF_ISLOT);
    unsigned short* Qh  = (unsigned short*)(ws + OFF_QH);
    unsigned short* Ql  = (unsigned short*)(ws + OFF_QL);
    unsigned short* Kh  = (unsigned short*)(ws + OFF_KH);
    unsigned short* Kl  = (unsigned short*)(ws + OFF_KL);
    unsigned short* Vth = (unsigned short*)(ws + OFF_VTH);
    unsigned short* Vtl = (unsigned short*)(ws + OFF_VTL);
    unsigned short* msgbuf = (unsigned short*)(ws + OFF_MSG);
    float* num = ws + OFF_NUM;
    float* den = ws + OFF_DEN;
    float* out = (float*)d_out;

    hipMemsetAsync(cnt, 0, NA * sizeof(int), stream);
    prep_all<<<512, 256, 0, stream>>>(We, state, be, pair, Bh, Vb, cnt);
    scan_kernel<<<1, 256, 0, stream>>>(cnt, cur, rp);
    scatter_kernel<<<512, 256, 0, stream>>>(pair, cur, islot);
    msg_mfma<<<NB / 128, 256, 0, stream>>>(atom, bond, Bh, Vb, pair, bg, islot, msgbuf);
    gru_kernel<<<3 * NA / 8, 256, 0, stream>>>(atom, msgbuf, rp, Wx, Wh, bx, bh,
                                               Qh, Ql, Kh, Kl, Vth, Vtl);
    attn_mfma<<<dim3(NA / 128, NSHARD), 256, 0, stream>>>(Qh, Ql, Kh, Kl, Vth, Vtl, num, den);
    merge_kernel<<<NA / 8, 256, 0, stream>>>(num, den, out);
}